// Round 7
// baseline (58.474 us; speedup 1.0000x reference)
//
#include <hip/hip_runtime.h>
#include <hip/hip_bf16.h>
#include <math.h>

#define NVOX 262144   // 64^3
#define BIGF 1e8f
#define GRID_A 2048   // stats/probs blocks (2 voxels/thread)
#define GRID_B 768    // EDT W+H blocks (b*192 + d*3 + cm)
#define GRID_K2 768   // EDT D + sdf blocks (combo*64 + h)

// ---- helpers ----
__device__ __forceinline__ unsigned short f2bf(float x) {
    __hip_bfloat16 h = __float2bfloat16(x);
    return *reinterpret_cast<unsigned short*>(&h);
}
__device__ __forceinline__ float bf2f(unsigned short u) {
    __hip_bfloat16 h = *reinterpret_cast<__hip_bfloat16*>(&u);
    return __bfloat162float(h);
}
// squared distance (u16, 0xFFFF = +inf) from lane w to nearest set bit of mask
__device__ __forceinline__ unsigned short dist2_u16(unsigned long long mask, int w) {
    if (mask == 0ull) return 0xFFFFu;
    unsigned long long mr = mask >> w;          // bits k >= w
    unsigned long long ml = mask << (63 - w);   // bits k <= w
    int dr = mr ? __builtin_ctzll(mr) : 127;
    int dl = ml ? __builtin_clzll(ml) : 127;
    int dd = dr < dl ? dr : dl;
    return (unsigned short)(dd * dd);
}

// =====================================================================
// kA2: streaming softmax stats + bf16 probsT. 2048 blocks x 256 thr,
// 2 voxels/thread -> 524288 threads = 32 waves/CU (full occupancy).
// exp2/log2/rcp native-instruction softmax (error ~1e-7, threshold 5e-2).
// probsT layout [combo][h][d][w] bf16 (contiguous in w => coalesced).
// =====================================================================
__global__ __launch_bounds__(256) void kA2_stats_probs(
    const float* __restrict__ preds, const int* __restrict__ targets,
    unsigned short* __restrict__ probsT, float* __restrict__ part_stats) {
    __shared__ float sred[4 * 13];
    int bid = blockIdx.x;
    int t = threadIdx.x, lane = t & 63, wid = t >> 6;
    int g0 = bid * 512 + 2 * t;          // voxel pair base in [0, 4*NVOX)
    int b = g0 >> 18;
    int v0 = g0 & (NVOX - 1);
    const float* p = preds + (size_t)(b * 4) * NVOX + v0;
    float2 x0 = *(const float2*)(p);
    float2 x1 = *(const float2*)(p + NVOX);
    float2 x2 = *(const float2*)(p + 2 * NVOX);
    float2 x3 = *(const float2*)(p + 3 * NVOX);
    int2 tv2 = *(const int2*)(targets + (size_t)b * NVOX + v0);

    const float L2E = 1.4426950408889634f;
    const float LN2 = 0.6931471805599453f;
    float q[13];
    #pragma unroll
    for (int k = 0; k < 13; ++k) q[k] = 0.0f;
    unsigned short pb[3][2];

    #pragma unroll
    for (int j = 0; j < 2; ++j) {
        float a0 = (&x0.x)[j], a1 = (&x1.x)[j], a2 = (&x2.x)[j], a3 = (&x3.x)[j];
        int tv = (&tv2.x)[j];
        float m  = fmaxf(fmaxf(a0, a1), fmaxf(a2, a3));
        float e0 = exp2f((a0 - m) * L2E);
        float e1 = exp2f((a1 - m) * L2E);
        float e2 = exp2f((a2 - m) * L2E);
        float e3 = exp2f((a3 - m) * L2E);
        float ssum = e0 + e1 + e2 + e3;
        float inv  = __builtin_amdgcn_rcpf(ssum);
        float p0 = e0 * inv, p1 = e1 * inv, p2 = e2 * inv, p3 = e3 * inv;
        float xt = (tv == 0) ? a0 : (tv == 1) ? a1 : (tv == 2) ? a2 : a3;
        q[12] += (m - xt) + log2f(ssum) * LN2;   // -log_softmax[target]
        q[4] += p0; q[5] += p1; q[6] += p2; q[7] += p3;
        if (tv == 0)      { q[0] += p0; q[8]  += 1.0f; }
        else if (tv == 1) { q[1] += p1; q[9]  += 1.0f; }
        else if (tv == 2) { q[2] += p2; q[10] += 1.0f; }
        else              { q[3] += p3; q[11] += 1.0f; }
        pb[0][j] = f2bf(p1); pb[1][j] = f2bf(p2); pb[2][j] = f2bf(p3);
    }

    int d = v0 >> 12, h = (v0 >> 6) & 63, w0 = v0 & 63;   // pair stays in one w-row
    size_t poff = (size_t)h * 4096 + d * 64 + w0;
    #pragma unroll
    for (int c = 0; c < 3; ++c) {
        ushort2 u = make_ushort2(pb[c][0], pb[c][1]);
        *(ushort2*)(probsT + (size_t)(b * 3 + c) * NVOX + poff) = u;
    }

    #pragma unroll
    for (int k = 0; k < 13; ++k) {
        float x = q[k];
        #pragma unroll
        for (int o = 32; o > 0; o >>= 1) x += __shfl_down(x, o);
        if (lane == 0) sred[wid * 13 + k] = x;
    }
    __syncthreads();
    if (t < 13) {
        float s = sred[t] + sred[13 + t] + sred[26 + t] + sred[39 + t];
        part_stats[t * 2048 + bid] = s;
    }
}

// =====================================================================
// kB: EDT pass-1 (W, ballot) + pass-2 (H, early-exit scan in LDS).
// grid = 768 (b*192 + d*3 + cm), 256 thr. Reads targets only.
// Writes bufA[combo + 12*v][h][d][w] (u16 squared dist, 0xFFFF = inf).
// =====================================================================
__global__ __launch_bounds__(256) void kB_edt12(
    const int* __restrict__ targets, unsigned short* __restrict__ bufA) {
    __shared__ float tO[64 * 65];
    __shared__ float tI[64 * 65];
    int blk = blockIdx.x;
    int cm = blk % 3;
    int bd = blk / 3;            // b*64 + d
    int d = bd & 63, b = bd >> 6;
    int c = cm + 1;
    int t = threadIdx.x, lane = t & 63, wid = t >> 6;
    const int* tg = targets + (size_t)b * NVOX + (size_t)d * 4096;

    #pragma unroll
    for (int i = 0; i < 16; ++i) {
        int e = t + 256 * i;
        int h = wid + 4 * i;
        int tv = tg[e];
        unsigned long long mask = __ballot(tv == c);
        unsigned short o  = dist2_u16(mask, lane);
        unsigned short ii = dist2_u16(~mask, lane);
        tO[h * 65 + lane] = (o  == 0xFFFFu) ? BIGF : (float)o;
        tI[h * 65 + lane] = (ii == 0xFFFFu) ? BIGF : (float)ii;
    }
    __syncthreads();

    // pass-2 along H: wave owns 16 cols w = wid*16+r; lane = h. Early-exit.
    for (int r = 0; r < 16; ++r) {
        int w = wid * 16 + r;
        {
            float best = tO[lane * 65 + w];
            for (int dk = 1; dk < 64; ++dk) {
                float d2 = (float)(dk * dk);
                if (__all(d2 >= best)) break;
                int hl = lane - dk; hl = hl < 0 ? 0 : hl;
                int hr = lane + dk; hr = hr > 63 ? 63 : hr;
                best = fminf(fminf(best, tO[hl * 65 + w] + d2), tO[hr * 65 + w] + d2);
            }
            tO[lane * 65 + w] = best;   // wave-lockstep: safe in-place
        }
        {
            float best = tI[lane * 65 + w];
            for (int dk = 1; dk < 64; ++dk) {
                float d2 = (float)(dk * dk);
                if (__all(d2 >= best)) break;
                int hl = lane - dk; hl = hl < 0 ? 0 : hl;
                int hr = lane + dk; hr = hr > 63 ? 63 : hr;
                best = fminf(fminf(best, tI[hl * 65 + w] + d2), tI[hr * 65 + w] + d2);
            }
            tI[lane * 65 + w] = best;
        }
    }
    __syncthreads();

    int combo = b * 3 + cm;
    size_t oO = (size_t)combo * NVOX + (size_t)d * 64;
    size_t oI = (size_t)(combo + 12) * NVOX + (size_t)d * 64;
    #pragma unroll
    for (int i = 0; i < 16; ++i) {
        int h = wid + 4 * i;
        float vo = tO[h * 65 + lane];
        float vi = tI[h * 65 + lane];
        bufA[oO + (size_t)h * 4096 + lane] = (vo >= 1e7f) ? 0xFFFFu : (unsigned short)vo;
        bufA[oI + (size_t)h * 4096 + lane] = (vi >= 1e7f) ? 0xFFFFu : (unsigned short)vi;
    }
}

// =====================================================================
// K2: EDT pass-3 (D, early-exit) + sdf*prob reduce -> one float per block.
// grid = 768 (combo*64 + h), 512 thr. All global accesses contiguous.
// =====================================================================
__global__ __launch_bounds__(512) void K2_edt3_sdf(
    const unsigned short* __restrict__ bufA, const unsigned short* __restrict__ probsT,
    float* __restrict__ part_bound) {
    __shared__ float pl[2][64 * 65];
    __shared__ float sredb[8];
    int blk = blockIdx.x;
    int combo = blk >> 6, h = blk & 63;
    int t = threadIdx.x, lane = t & 63, wid = t >> 6;

    for (int v = 0; v < 2; ++v) {
        const unsigned short* src = bufA + (size_t)(combo + 12 * v) * NVOX + (size_t)h * 4096;
        #pragma unroll
        for (int i = 0; i < 8; ++i) {
            int e = t + 512 * i;                     // e = d*64 + w
            unsigned short u = src[e];
            pl[v][e + (e >> 6)] = (u == 0xFFFFu) ? BIGF : (float)u;   // lds[d*65+w]
        }
    }
    __syncthreads();

    // pass along D: wave owns cols w = wid*8+r; lane = d. Early-exit.
    for (int v = 0; v < 2; ++v) {
        for (int r = 0; r < 8; ++r) {
            int w = wid * 8 + r;
            float* col = &pl[v][w];
            float best = col[lane * 65];
            for (int dk = 1; dk < 64; ++dk) {
                float d2 = (float)(dk * dk);
                if (__all(d2 >= best)) break;
                int dl = lane - dk; dl = dl < 0 ? 0 : dl;
                int dr = lane + dk; dr = dr > 63 ? 63 : dr;
                best = fminf(fminf(best, col[dl * 65] + d2), col[dr * 65] + d2);
            }
            col[lane * 65] = best;
        }
    }
    __syncthreads();

    const unsigned short* pp = probsT + (size_t)combo * NVOX + (size_t)h * 4096;
    float acc = 0.0f;
    #pragma unroll
    for (int i = 0; i < 8; ++i) {
        int e = t + 512 * i;
        int li = e + (e >> 6);
        float sdf = sqrtf(pl[0][li]) - sqrtf(pl[1][li]);
        acc += sdf * bf2f(pp[e]);
    }
    #pragma unroll
    for (int o = 32; o > 0; o >>= 1) acc += __shfl_down(acc, o);
    if (lane == 0) sredb[wid] = acc;
    __syncthreads();
    if (t == 0) {
        float s = 0.0f;
        for (int j = 0; j < 8; ++j) s += sredb[j];
        part_bound[blk] = s;
    }
}

// =====================================================================
// K3: single block; all loads up-front, shfl/LDS reduce, f64 combine.
// part_stats rows are 2048 wide (512 blocks per batch b; b = entry>>9).
// =====================================================================
__global__ __launch_bounds__(1024) void K3_final(
    const float* __restrict__ part_stats, const float* __restrict__ part_bound,
    float* __restrict__ out) {
    __shared__ float sredA[13 * 16];
    __shared__ float sredB[13 * 16];
    __shared__ float bred[12];
    __shared__ double S[52];
    int t = threadIdx.x, lane = t & 63, wid = t >> 6;

    float vA[13], vB[13];
    #pragma unroll
    for (int k = 0; k < 13; ++k) {
        vA[k] = part_stats[k * 2048 + t];          // entries 0..1023   (b = 0,1)
        vB[k] = part_stats[k * 2048 + 1024 + t];   // entries 1024..2047 (b = 2,3)
    }
    float bv = (wid < 12) ? part_bound[wid * 64 + lane] : 0.0f;

    #pragma unroll
    for (int k = 0; k < 13; ++k) {
        float xa = vA[k], xb = vB[k];
        #pragma unroll
        for (int o = 32; o > 0; o >>= 1) { xa += __shfl_down(xa, o); xb += __shfl_down(xb, o); }
        if (lane == 0) { sredA[k * 16 + wid] = xa; sredB[k * 16 + wid] = xb; }
    }
    #pragma unroll
    for (int o = 32; o > 0; o >>= 1) bv += __shfl_down(bv, o);
    if (lane == 0 && wid < 12) bred[wid] = bv;
    __syncthreads();

    if (t < 52) {   // k = t>>2, bsel = t&3; 8 waves (x64 lanes = 512 entries) per b
        int k = t >> 2, bsel = t & 3;
        const float* src = (bsel < 2) ? sredA : sredB;
        int base = k * 16 + (bsel & 1) * 8;
        double s = 0.0;
        for (int j = 0; j < 8; ++j) s += (double)src[base + j];
        S[k * 4 + bsel] = s;
    }
    __syncthreads();
    if (t == 0) {
        const double NV = (double)NVOX;
        double dice_sum = 0.0;
        for (int b = 0; b < 4; ++b)
            for (int c = 0; c < 4; ++c) {
                double inter = S[c * 4 + b];
                double un    = S[(4 + c) * 4 + b] + S[(8 + c) * 4 + b];
                dice_sum += (2.0 * inter + 1e-5) / (un + 1e-5);
            }
        double l_dice = 1.0 - dice_sum / 16.0;
        double l_ce = (S[48] + S[49] + S[50] + S[51]) / (4.0 * NV);
        double lb = 0.0;
        for (int cb = 0; cb < 12; ++cb) {
            int b = cb / 3, c = cb % 3 + 1;
            double cnt = S[(8 + c) * 4 + b];
            double s;
            if (cnt == 0.0)      s =  S[(4 + c) * 4 + b];   // sdf == +1 everywhere
            else if (cnt == NV)  s = -S[(4 + c) * 4 + b];   // sdf == -1 everywhere
            else                 s =  (double)bred[cb];
            lb += s / NV;
        }
        lb /= 12.0;
        out[0] = (float)(l_dice + l_ce + 0.01 * lb);
    }
}

extern "C" void kernel_launch(void* const* d_in, const int* in_sizes, int n_in,
                              void* d_out, int out_size, void* d_ws, size_t ws_size,
                              hipStream_t stream) {
    const float* preds   = (const float*)d_in[0];
    const int*   targets = (const int*)d_in[1];
    float* out = (float*)d_out;

    // workspace: bufA u16 (12.6 MB) | probsT bf16 (6.3 MB) | partials (~110 KB)
    unsigned short* bufA   = (unsigned short*)d_ws;
    unsigned short* probsT = bufA + (size_t)24 * NVOX;
    float* part_stats = (float*)(probsT + (size_t)12 * NVOX);
    float* part_bound = part_stats + 13 * 2048;

    kA2_stats_probs<<<GRID_A, 256, 0, stream>>>(preds, targets, probsT, part_stats);
    kB_edt12<<<GRID_B, 256, 0, stream>>>(targets, bufA);
    K2_edt3_sdf<<<GRID_K2, 512, 0, stream>>>(bufA, probsT, part_bound);
    K3_final<<<1, 1024, 0, stream>>>(part_stats, part_bound, out);
}

// Round 8
// 56.456 us; speedup vs baseline: 1.0358x; 1.0358x over previous
//
#include <hip/hip_runtime.h>
#include <hip/hip_bf16.h>
#include <math.h>

#define NVOX 262144   // 64^3
#define BIGF 1e8f
#define GRID_B 768    // EDT W+H blocks (b*192 + d*3 + cm)
#define GRID_K2 768   // EDT D + sdf blocks (combo*64 + h)

// ---- helpers ----
__device__ __forceinline__ unsigned short f2bf(float x) {
    __hip_bfloat16 h = __float2bfloat16(x);
    return *reinterpret_cast<unsigned short*>(&h);
}
__device__ __forceinline__ float bf2f(unsigned short u) {
    __hip_bfloat16 h = *reinterpret_cast<__hip_bfloat16*>(&u);
    return __bfloat162float(h);
}
// squared distance (u16, 0xFFFF acts as +inf) from lane w to nearest set bit
__device__ __forceinline__ unsigned short dist2_u16(unsigned long long mask, int w) {
    if (mask == 0ull) return 0xFFFFu;
    unsigned long long mr = mask >> w;          // bits k >= w
    unsigned long long ml = mask << (63 - w);   // bits k <= w
    int dr = mr ? __builtin_ctzll(mr) : 127;
    int dl = ml ? __builtin_clzll(ml) : 127;
    int dd = dr < dl ? dr : dl;
    return (unsigned short)(dd * dd);
}

// =====================================================================
// kA_probs: PURE softmax->bf16 probsT stream. 1024 blocks x 256 thr,
// 4 voxels/thread (float4). No targets, no LDS, no shuffles, no branches.
// probsT[combo][h][d][w] bf16: 4 consecutive w per thread => ushort4.
// =====================================================================
__global__ __launch_bounds__(256) void kA_probs(
    const float* __restrict__ preds, unsigned short* __restrict__ probsT) {
    int bid = blockIdx.x, t = threadIdx.x;
    int g0 = bid * 1024 + 4 * t;
    int b = g0 >> 18;
    int v0 = g0 & (NVOX - 1);
    const float* p = preds + (size_t)(b * 4) * NVOX + v0;
    float4 x0 = *(const float4*)(p);
    float4 x1 = *(const float4*)(p + NVOX);
    float4 x2 = *(const float4*)(p + 2 * NVOX);
    float4 x3 = *(const float4*)(p + 3 * NVOX);

    const float L2E = 1.4426950408889634f;
    unsigned short pb[3][4];
    #pragma unroll
    for (int j = 0; j < 4; ++j) {
        float a0 = (&x0.x)[j], a1 = (&x1.x)[j], a2 = (&x2.x)[j], a3 = (&x3.x)[j];
        float m  = fmaxf(fmaxf(a0, a1), fmaxf(a2, a3));
        float e0 = exp2f((a0 - m) * L2E);
        float e1 = exp2f((a1 - m) * L2E);
        float e2 = exp2f((a2 - m) * L2E);
        float e3 = exp2f((a3 - m) * L2E);
        float inv = __builtin_amdgcn_rcpf(e0 + e1 + e2 + e3);
        pb[0][j] = f2bf(e1 * inv);
        pb[1][j] = f2bf(e2 * inv);
        pb[2][j] = f2bf(e3 * inv);
    }
    int d = v0 >> 12, h = (v0 >> 6) & 63, w0 = v0 & 63;
    size_t poff = (size_t)h * 4096 + d * 64 + w0;
    #pragma unroll
    for (int c = 0; c < 3; ++c) {
        ushort4 u = make_ushort4(pb[c][0], pb[c][1], pb[c][2], pb[c][3]);
        *(ushort4*)(probsT + (size_t)(b * 3 + c) * NVOX + poff) = u;
    }
}

// =====================================================================
// kA_stats: dice/CE partials ONLY. 1024 blocks x 256 thr, 4 vox/thread.
// Reads preds (L3-warm) + targets; writes 13 floats per block.
// =====================================================================
__global__ __launch_bounds__(256) void kA_stats(
    const float* __restrict__ preds, const int* __restrict__ targets,
    float* __restrict__ part_stats) {
    __shared__ float sred[4 * 13];
    int bid = blockIdx.x, t = threadIdx.x, lane = t & 63, wid = t >> 6;
    int g0 = bid * 1024 + 4 * t;
    int b = g0 >> 18;
    int v0 = g0 & (NVOX - 1);
    const float* p = preds + (size_t)(b * 4) * NVOX + v0;
    float4 x0 = *(const float4*)(p);
    float4 x1 = *(const float4*)(p + NVOX);
    float4 x2 = *(const float4*)(p + 2 * NVOX);
    float4 x3 = *(const float4*)(p + 3 * NVOX);
    int4 tv4 = *(const int4*)(targets + (size_t)b * NVOX + v0);

    const float L2E = 1.4426950408889634f;
    const float LN2 = 0.6931471805599453f;
    float q[13];
    #pragma unroll
    for (int k = 0; k < 13; ++k) q[k] = 0.0f;

    #pragma unroll
    for (int j = 0; j < 4; ++j) {
        float a0 = (&x0.x)[j], a1 = (&x1.x)[j], a2 = (&x2.x)[j], a3 = (&x3.x)[j];
        int tv = (&tv4.x)[j];
        float m  = fmaxf(fmaxf(a0, a1), fmaxf(a2, a3));
        float e0 = exp2f((a0 - m) * L2E);
        float e1 = exp2f((a1 - m) * L2E);
        float e2 = exp2f((a2 - m) * L2E);
        float e3 = exp2f((a3 - m) * L2E);
        float ssum = e0 + e1 + e2 + e3;
        float inv  = __builtin_amdgcn_rcpf(ssum);
        float p0 = e0 * inv, p1 = e1 * inv, p2 = e2 * inv, p3 = e3 * inv;
        float xt = (tv == 0) ? a0 : (tv == 1) ? a1 : (tv == 2) ? a2 : a3;
        q[12] += (m - xt) + log2f(ssum) * LN2;
        q[4] += p0; q[5] += p1; q[6] += p2; q[7] += p3;
        if (tv == 0)      { q[0] += p0; q[8]  += 1.0f; }
        else if (tv == 1) { q[1] += p1; q[9]  += 1.0f; }
        else if (tv == 2) { q[2] += p2; q[10] += 1.0f; }
        else              { q[3] += p3; q[11] += 1.0f; }
    }

    #pragma unroll
    for (int k = 0; k < 13; ++k) {
        float x = q[k];
        #pragma unroll
        for (int o = 32; o > 0; o >>= 1) x += __shfl_down(x, o);
        if (lane == 0) sred[wid * 13 + k] = x;
    }
    __syncthreads();
    if (t < 13) {
        float s = sred[t] + sred[13 + t] + sred[26 + t] + sred[39 + t];
        part_stats[t * 1024 + bid] = s;
    }
}

// =====================================================================
// kB: EDT pass-1 (W, ballot) + pass-2 (H, early-exit) in u16 LDS tiles.
// 65535 acts as +inf: center candidate (no +d2) caps best at 65535; any
// real candidate (<= 11907) beats 65535+d2, so results are exact.
// grid = 768 (b*192 + d*3 + cm), 256 thr. LDS 16.9 KB -> 8 blocks/CU.
// =====================================================================
__global__ __launch_bounds__(256) void kB_edt12(
    const int* __restrict__ targets, unsigned short* __restrict__ bufA) {
    __shared__ unsigned short tO[64 * 66];
    __shared__ unsigned short tI[64 * 66];
    int blk = blockIdx.x;
    int cm = blk % 3;
    int bd = blk / 3;            // b*64 + d
    int d = bd & 63, b = bd >> 6;
    int c = cm + 1;
    int t = threadIdx.x, lane = t & 63, wid = t >> 6;
    const int* tg = targets + (size_t)b * NVOX + (size_t)d * 4096;

    #pragma unroll
    for (int i = 0; i < 16; ++i) {
        int e = t + 256 * i;
        int h = wid + 4 * i;
        int tv = tg[e];
        unsigned long long mask = __ballot(tv == c);
        tO[h * 66 + lane] = dist2_u16(mask, lane);
        tI[h * 66 + lane] = dist2_u16(~mask, lane);
    }
    __syncthreads();

    // pass-2 along H: wave owns 16 cols w = wid*16+r; lane = h. Early-exit.
    for (int r = 0; r < 16; ++r) {
        int w = wid * 16 + r;
        {
            float best = (float)tO[lane * 66 + w];
            for (int dk = 1; dk < 64; ++dk) {
                float d2 = (float)(dk * dk);
                if (__all(d2 >= best)) break;
                int hl = lane - dk; hl = hl < 0 ? 0 : hl;
                int hr = lane + dk; hr = hr > 63 ? 63 : hr;
                best = fminf(fminf(best, (float)tO[hl * 66 + w] + d2),
                             (float)tO[hr * 66 + w] + d2);
            }
            tO[lane * 66 + w] = (unsigned short)best;   // lockstep: safe in-place
        }
        {
            float best = (float)tI[lane * 66 + w];
            for (int dk = 1; dk < 64; ++dk) {
                float d2 = (float)(dk * dk);
                if (__all(d2 >= best)) break;
                int hl = lane - dk; hl = hl < 0 ? 0 : hl;
                int hr = lane + dk; hr = hr > 63 ? 63 : hr;
                best = fminf(fminf(best, (float)tI[hl * 66 + w] + d2),
                             (float)tI[hr * 66 + w] + d2);
            }
            tI[lane * 66 + w] = (unsigned short)best;
        }
    }
    __syncthreads();

    int combo = b * 3 + cm;
    size_t oO = (size_t)combo * NVOX + (size_t)d * 64;
    size_t oI = (size_t)(combo + 12) * NVOX + (size_t)d * 64;
    #pragma unroll
    for (int i = 0; i < 16; ++i) {
        int h = wid + 4 * i;
        bufA[oO + (size_t)h * 4096 + lane] = tO[h * 66 + lane];
        bufA[oI + (size_t)h * 4096 + lane] = tI[h * 66 + lane];
    }
}

// =====================================================================
// K2: EDT pass-3 (D, early-exit) + sdf*prob reduce -> one float per block.
// grid = 768 (combo*64 + h), 512 thr. 65535-as-inf, no sentinel selects.
// =====================================================================
__global__ __launch_bounds__(512) void K2_edt3_sdf(
    const unsigned short* __restrict__ bufA, const unsigned short* __restrict__ probsT,
    float* __restrict__ part_bound) {
    __shared__ float pl[2][64 * 65];
    __shared__ float sredb[8];
    int blk = blockIdx.x;
    int combo = blk >> 6, h = blk & 63;
    int t = threadIdx.x, lane = t & 63, wid = t >> 6;

    for (int v = 0; v < 2; ++v) {
        const unsigned short* src = bufA + (size_t)(combo + 12 * v) * NVOX + (size_t)h * 4096;
        #pragma unroll
        for (int i = 0; i < 8; ++i) {
            int e = t + 512 * i;                     // e = d*64 + w
            pl[v][e + (e >> 6)] = (float)src[e];     // lds[d*65+w]
        }
    }
    __syncthreads();

    // pass along D: wave owns cols w = wid*8+r; lane = d. Early-exit.
    for (int v = 0; v < 2; ++v) {
        for (int r = 0; r < 8; ++r) {
            int w = wid * 8 + r;
            float* col = &pl[v][w];
            float best = col[lane * 65];
            for (int dk = 1; dk < 64; ++dk) {
                float d2 = (float)(dk * dk);
                if (__all(d2 >= best)) break;
                int dl = lane - dk; dl = dl < 0 ? 0 : dl;
                int dr = lane + dk; dr = dr > 63 ? 63 : dr;
                best = fminf(fminf(best, col[dl * 65] + d2), col[dr * 65] + d2);
            }
            col[lane * 65] = best;
        }
    }
    __syncthreads();

    const unsigned short* pp = probsT + (size_t)combo * NVOX + (size_t)h * 4096;
    float acc = 0.0f;
    #pragma unroll
    for (int i = 0; i < 8; ++i) {
        int e = t + 512 * i;
        int li = e + (e >> 6);
        float sdf = sqrtf(pl[0][li]) - sqrtf(pl[1][li]);
        acc += sdf * bf2f(pp[e]);
    }
    #pragma unroll
    for (int o = 32; o > 0; o >>= 1) acc += __shfl_down(acc, o);
    if (lane == 0) sredb[wid] = acc;
    __syncthreads();
    if (t == 0) {
        float s = 0.0f;
        for (int j = 0; j < 8; ++j) s += sredb[j];
        part_bound[blk] = s;
    }
}

// =====================================================================
// K3: single block; loads up-front, shfl/LDS reduce, f64 combine + guards.
// part_stats rows 1024 wide (256 blocks per batch; b = entry>>8).
// =====================================================================
__global__ __launch_bounds__(1024) void K3_final(
    const float* __restrict__ part_stats, const float* __restrict__ part_bound,
    float* __restrict__ out) {
    __shared__ float sred[13 * 16];
    __shared__ float bred[12];
    __shared__ double S[52];
    int t = threadIdx.x, lane = t & 63, wid = t >> 6;

    float v[13];
    #pragma unroll
    for (int k = 0; k < 13; ++k) v[k] = part_stats[k * 1024 + t];
    float bv = (wid < 12) ? part_bound[wid * 64 + lane] : 0.0f;

    #pragma unroll
    for (int k = 0; k < 13; ++k) {
        float x = v[k];
        #pragma unroll
        for (int o = 32; o > 0; o >>= 1) x += __shfl_down(x, o);
        if (lane == 0) sred[k * 16 + wid] = x;
    }
    #pragma unroll
    for (int o = 32; o > 0; o >>= 1) bv += __shfl_down(bv, o);
    if (lane == 0 && wid < 12) bred[wid] = bv;
    __syncthreads();

    if (t < 52) {   // k = t>>2, b = t&3; 4 waves per b
        int k = t >> 2, b = t & 3;
        S[k * 4 + b] = (double)sred[k * 16 + b * 4]     + (double)sred[k * 16 + b * 4 + 1]
                     + (double)sred[k * 16 + b * 4 + 2] + (double)sred[k * 16 + b * 4 + 3];
    }
    __syncthreads();
    if (t == 0) {
        const double NV = (double)NVOX;
        double dice_sum = 0.0;
        for (int b = 0; b < 4; ++b)
            for (int c = 0; c < 4; ++c) {
                double inter = S[c * 4 + b];
                double un    = S[(4 + c) * 4 + b] + S[(8 + c) * 4 + b];
                dice_sum += (2.0 * inter + 1e-5) / (un + 1e-5);
            }
        double l_dice = 1.0 - dice_sum / 16.0;
        double l_ce = (S[48] + S[49] + S[50] + S[51]) / (4.0 * NV);
        double lb = 0.0;
        for (int cb = 0; cb < 12; ++cb) {
            int b = cb / 3, c = cb % 3 + 1;
            double cnt = S[(8 + c) * 4 + b];
            double s;
            if (cnt == 0.0)      s =  S[(4 + c) * 4 + b];   // sdf == +1 everywhere
            else if (cnt == NV)  s = -S[(4 + c) * 4 + b];   // sdf == -1 everywhere
            else                 s =  (double)bred[cb];
            lb += s / NV;
        }
        lb /= 12.0;
        out[0] = (float)(l_dice + l_ce + 0.01 * lb);
    }
}

extern "C" void kernel_launch(void* const* d_in, const int* in_sizes, int n_in,
                              void* d_out, int out_size, void* d_ws, size_t ws_size,
                              hipStream_t stream) {
    const float* preds   = (const float*)d_in[0];
    const int*   targets = (const int*)d_in[1];
    float* out = (float*)d_out;

    // workspace: bufA u16 (12.6 MB) | probsT bf16 (6.3 MB) | partials (~56 KB)
    unsigned short* bufA   = (unsigned short*)d_ws;
    unsigned short* probsT = bufA + (size_t)24 * NVOX;
    float* part_stats = (float*)(probsT + (size_t)12 * NVOX);
    float* part_bound = part_stats + 13 * 1024;

    kA_probs<<<1024, 256, 0, stream>>>(preds, probsT);
    kA_stats<<<1024, 256, 0, stream>>>(preds, targets, part_stats);
    kB_edt12<<<GRID_B, 256, 0, stream>>>(targets, bufA);
    K2_edt3_sdf<<<GRID_K2, 512, 0, stream>>>(bufA, probsT, part_bound);
    K3_final<<<1, 1024, 0, stream>>>(part_stats, part_bound, out);
}

// Round 9
// 54.535 us; speedup vs baseline: 1.0722x; 1.0352x over previous
//
#include <hip/hip_runtime.h>
#include <hip/hip_bf16.h>
#include <math.h>

#define NVOX 262144   // 64^3
#define BIGF 1e8f
#define GRID_B 768    // EDT W+H blocks (b*192 + d*3 + cm)
#define GRID_K2 768   // EDT D + sdf blocks (combo*64 + h)

// ---- helpers ----
__device__ __forceinline__ unsigned short f2bf(float x) {
    __hip_bfloat16 h = __float2bfloat16(x);
    return *reinterpret_cast<unsigned short*>(&h);
}
__device__ __forceinline__ float bf2f(unsigned short u) {
    __hip_bfloat16 h = *reinterpret_cast<__hip_bfloat16*>(&u);
    return __bfloat162float(h);
}
// squared distance (u16, 0xFFFF acts as +inf) from lane w to nearest set bit
__device__ __forceinline__ unsigned short dist2_u16(unsigned long long mask, int w) {
    if (mask == 0ull) return 0xFFFFu;
    unsigned long long mr = mask >> w;          // bits k >= w
    unsigned long long ml = mask << (63 - w);   // bits k <= w
    int dr = mr ? __builtin_ctzll(mr) : 127;
    int dl = ml ? __builtin_clzll(ml) : 127;
    int dd = dr < dl ? dr : dl;
    return (unsigned short)(dd * dd);
}

__device__ __forceinline__ void softmax_quad(
    const float4& x0, const float4& x1, const float4& x2, const float4& x3,
    const int4& tv4, float* q, unsigned short pb[3][4]) {
    const float L2E = 1.4426950408889634f;
    const float LN2 = 0.6931471805599453f;
    #pragma unroll
    for (int j = 0; j < 4; ++j) {
        float a0 = (&x0.x)[j], a1 = (&x1.x)[j], a2 = (&x2.x)[j], a3 = (&x3.x)[j];
        int tv = (&tv4.x)[j];
        float m  = fmaxf(fmaxf(a0, a1), fmaxf(a2, a3));
        float e0 = exp2f((a0 - m) * L2E);
        float e1 = exp2f((a1 - m) * L2E);
        float e2 = exp2f((a2 - m) * L2E);
        float e3 = exp2f((a3 - m) * L2E);
        float ssum = e0 + e1 + e2 + e3;
        float inv  = __builtin_amdgcn_rcpf(ssum);
        float p0 = e0 * inv, p1 = e1 * inv, p2 = e2 * inv, p3 = e3 * inv;
        float xt = (tv == 0) ? a0 : (tv == 1) ? a1 : (tv == 2) ? a2 : a3;
        q[12] += (m - xt) + log2f(ssum) * LN2;
        q[4] += p0; q[5] += p1; q[6] += p2; q[7] += p3;
        if (tv == 0)      { q[0] += p0; q[8]  += 1.0f; }
        else if (tv == 1) { q[1] += p1; q[9]  += 1.0f; }
        else if (tv == 2) { q[2] += p2; q[10] += 1.0f; }
        else              { q[3] += p3; q[11] += 1.0f; }
        pb[0][j] = f2bf(p1); pb[1][j] = f2bf(p2); pb[2][j] = f2bf(p3);
    }
}

// =====================================================================
// kAx: merged stats + probsT, 2 voxel-quads per thread (batches b0 and
// b0+2 at the same intra-volume offset). 512 blocks x 256 thr.
// 10 independent global loads issued up-front per thread (MLP).
// part_stats layout: [k][b][256] -> index k*1024 + b*256 + (bid&255).
// =====================================================================
__global__ __launch_bounds__(256) void kAx_stats_probs(
    const float* __restrict__ preds, const int* __restrict__ targets,
    unsigned short* __restrict__ probsT, float* __restrict__ part_stats) {
    __shared__ float sred[4 * 26];
    int bid = blockIdx.x, t = threadIdx.x, lane = t & 63, wid = t >> 6;
    int T = bid * 256 + t;                 // [0, 131072)
    int v0 = (4 * T) & (NVOX - 1);         // same offset for both quads
    int b0 = T >> 16;                      // 0 or 1 (uniform per block)
    int b1 = b0 + 2;

    const float* pA = preds + (size_t)(b0 * 4) * NVOX + v0;
    const float* pB = preds + (size_t)(b1 * 4) * NVOX + v0;
    // issue all 10 loads before any use
    float4 a0 = *(const float4*)(pA);
    float4 a1 = *(const float4*)(pA + NVOX);
    float4 a2 = *(const float4*)(pA + 2 * NVOX);
    float4 a3 = *(const float4*)(pA + 3 * NVOX);
    float4 c0 = *(const float4*)(pB);
    float4 c1 = *(const float4*)(pB + NVOX);
    float4 c2 = *(const float4*)(pB + 2 * NVOX);
    float4 c3 = *(const float4*)(pB + 3 * NVOX);
    int4 tvA = *(const int4*)(targets + (size_t)b0 * NVOX + v0);
    int4 tvB = *(const int4*)(targets + (size_t)b1 * NVOX + v0);

    float qA[13], qB[13];
    #pragma unroll
    for (int k = 0; k < 13; ++k) { qA[k] = 0.0f; qB[k] = 0.0f; }
    unsigned short pbA[3][4], pbB[3][4];
    softmax_quad(a0, a1, a2, a3, tvA, qA, pbA);
    softmax_quad(c0, c1, c2, c3, tvB, qB, pbB);

    int d = v0 >> 12, h = (v0 >> 6) & 63, w0 = v0 & 63;
    size_t poff = (size_t)h * 4096 + d * 64 + w0;
    #pragma unroll
    for (int c = 0; c < 3; ++c) {
        *(ushort4*)(probsT + (size_t)(b0 * 3 + c) * NVOX + poff) =
            make_ushort4(pbA[c][0], pbA[c][1], pbA[c][2], pbA[c][3]);
        *(ushort4*)(probsT + (size_t)(b1 * 3 + c) * NVOX + poff) =
            make_ushort4(pbB[c][0], pbB[c][1], pbB[c][2], pbB[c][3]);
    }

    #pragma unroll
    for (int k = 0; k < 13; ++k) {
        float xa = qA[k], xb = qB[k];
        #pragma unroll
        for (int o = 32; o > 0; o >>= 1) { xa += __shfl_down(xa, o); xb += __shfl_down(xb, o); }
        if (lane == 0) { sred[wid * 26 + k] = xa; sred[wid * 26 + 13 + k] = xb; }
    }
    __syncthreads();
    if (t < 26) {
        int k = (t < 13) ? t : t - 13;
        int b = (t < 13) ? b0 : b1;
        float s = sred[t] + sred[26 + t] + sred[52 + t] + sred[78 + t];
        part_stats[k * 1024 + b * 256 + (bid & 255)] = s;
    }
}

// =====================================================================
// kB: EDT pass-1 (W, ballot) + pass-2 (H, early-exit) in u16 LDS tiles.
// 65535 acts as +inf: center candidate (no +d2) caps best at 65535; any
// real candidate (<= 11907) beats 65535+d2, so results are exact.
// grid = 768 (b*192 + d*3 + cm), 256 thr.
// =====================================================================
__global__ __launch_bounds__(256) void kB_edt12(
    const int* __restrict__ targets, unsigned short* __restrict__ bufA) {
    __shared__ unsigned short tO[64 * 66];
    __shared__ unsigned short tI[64 * 66];
    int blk = blockIdx.x;
    int cm = blk % 3;
    int bd = blk / 3;            // b*64 + d
    int d = bd & 63, b = bd >> 6;
    int c = cm + 1;
    int t = threadIdx.x, lane = t & 63, wid = t >> 6;
    const int* tg = targets + (size_t)b * NVOX + (size_t)d * 4096;

    #pragma unroll
    for (int i = 0; i < 16; ++i) {
        int e = t + 256 * i;
        int h = wid + 4 * i;
        int tv = tg[e];
        unsigned long long mask = __ballot(tv == c);
        tO[h * 66 + lane] = dist2_u16(mask, lane);
        tI[h * 66 + lane] = dist2_u16(~mask, lane);
    }
    __syncthreads();

    // pass-2 along H: wave owns 16 cols w = wid*16+r; lane = h. Early-exit.
    for (int r = 0; r < 16; ++r) {
        int w = wid * 16 + r;
        {
            float best = (float)tO[lane * 66 + w];
            for (int dk = 1; dk < 64; ++dk) {
                float d2 = (float)(dk * dk);
                if (__all(d2 >= best)) break;
                int hl = lane - dk; hl = hl < 0 ? 0 : hl;
                int hr = lane + dk; hr = hr > 63 ? 63 : hr;
                best = fminf(fminf(best, (float)tO[hl * 66 + w] + d2),
                             (float)tO[hr * 66 + w] + d2);
            }
            tO[lane * 66 + w] = (unsigned short)best;   // lockstep: safe in-place
        }
        {
            float best = (float)tI[lane * 66 + w];
            for (int dk = 1; dk < 64; ++dk) {
                float d2 = (float)(dk * dk);
                if (__all(d2 >= best)) break;
                int hl = lane - dk; hl = hl < 0 ? 0 : hl;
                int hr = lane + dk; hr = hr > 63 ? 63 : hr;
                best = fminf(fminf(best, (float)tI[hl * 66 + w] + d2),
                             (float)tI[hr * 66 + w] + d2);
            }
            tI[lane * 66 + w] = (unsigned short)best;
        }
    }
    __syncthreads();

    int combo = b * 3 + cm;
    size_t oO = (size_t)combo * NVOX + (size_t)d * 64;
    size_t oI = (size_t)(combo + 12) * NVOX + (size_t)d * 64;
    #pragma unroll
    for (int i = 0; i < 16; ++i) {
        int h = wid + 4 * i;
        bufA[oO + (size_t)h * 4096 + lane] = tO[h * 66 + lane];
        bufA[oI + (size_t)h * 4096 + lane] = tI[h * 66 + lane];
    }
}

// =====================================================================
// K2: EDT pass-3 (D, early-exit) + sdf*prob reduce -> one float per block.
// grid = 768 (combo*64 + h), 512 thr. 65535-as-inf, no sentinel selects.
// =====================================================================
__global__ __launch_bounds__(512) void K2_edt3_sdf(
    const unsigned short* __restrict__ bufA, const unsigned short* __restrict__ probsT,
    float* __restrict__ part_bound) {
    __shared__ float pl[2][64 * 65];
    __shared__ float sredb[8];
    int blk = blockIdx.x;
    int combo = blk >> 6, h = blk & 63;
    int t = threadIdx.x, lane = t & 63, wid = t >> 6;

    for (int v = 0; v < 2; ++v) {
        const unsigned short* src = bufA + (size_t)(combo + 12 * v) * NVOX + (size_t)h * 4096;
        #pragma unroll
        for (int i = 0; i < 8; ++i) {
            int e = t + 512 * i;                     // e = d*64 + w
            pl[v][e + (e >> 6)] = (float)src[e];     // lds[d*65+w]
        }
    }
    __syncthreads();

    // pass along D: wave owns cols w = wid*8+r; lane = d. Early-exit.
    for (int v = 0; v < 2; ++v) {
        for (int r = 0; r < 8; ++r) {
            int w = wid * 8 + r;
            float* col = &pl[v][w];
            float best = col[lane * 65];
            for (int dk = 1; dk < 64; ++dk) {
                float d2 = (float)(dk * dk);
                if (__all(d2 >= best)) break;
                int dl = lane - dk; dl = dl < 0 ? 0 : dl;
                int dr = lane + dk; dr = dr > 63 ? 63 : dr;
                best = fminf(fminf(best, col[dl * 65] + d2), col[dr * 65] + d2);
            }
            col[lane * 65] = best;
        }
    }
    __syncthreads();

    const unsigned short* pp = probsT + (size_t)combo * NVOX + (size_t)h * 4096;
    float acc = 0.0f;
    #pragma unroll
    for (int i = 0; i < 8; ++i) {
        int e = t + 512 * i;
        int li = e + (e >> 6);
        float sdf = sqrtf(pl[0][li]) - sqrtf(pl[1][li]);
        acc += sdf * bf2f(pp[e]);
    }
    #pragma unroll
    for (int o = 32; o > 0; o >>= 1) acc += __shfl_down(acc, o);
    if (lane == 0) sredb[wid] = acc;
    __syncthreads();
    if (t == 0) {
        float s = 0.0f;
        for (int j = 0; j < 8; ++j) s += sredb[j];
        part_bound[blk] = s;
    }
}

// =====================================================================
// K3: single block; loads up-front, shfl/LDS reduce, f64 combine + guards.
// part_stats rows 1024 wide: [k][b][256].
// =====================================================================
__global__ __launch_bounds__(1024) void K3_final(
    const float* __restrict__ part_stats, const float* __restrict__ part_bound,
    float* __restrict__ out) {
    __shared__ float sred[13 * 16];
    __shared__ float bred[12];
    __shared__ double S[52];
    int t = threadIdx.x, lane = t & 63, wid = t >> 6;

    float v[13];
    #pragma unroll
    for (int k = 0; k < 13; ++k) v[k] = part_stats[k * 1024 + t];
    float bv = (wid < 12) ? part_bound[wid * 64 + lane] : 0.0f;

    #pragma unroll
    for (int k = 0; k < 13; ++k) {
        float x = v[k];
        #pragma unroll
        for (int o = 32; o > 0; o >>= 1) x += __shfl_down(x, o);
        if (lane == 0) sred[k * 16 + wid] = x;
    }
    #pragma unroll
    for (int o = 32; o > 0; o >>= 1) bv += __shfl_down(bv, o);
    if (lane == 0 && wid < 12) bred[wid] = bv;
    __syncthreads();

    if (t < 52) {   // k = t>>2, b = t&3; 4 waves per b
        int k = t >> 2, b = t & 3;
        S[k * 4 + b] = (double)sred[k * 16 + b * 4]     + (double)sred[k * 16 + b * 4 + 1]
                     + (double)sred[k * 16 + b * 4 + 2] + (double)sred[k * 16 + b * 4 + 3];
    }
    __syncthreads();
    if (t == 0) {
        const double NV = (double)NVOX;
        double dice_sum = 0.0;
        for (int b = 0; b < 4; ++b)
            for (int c = 0; c < 4; ++c) {
                double inter = S[c * 4 + b];
                double un    = S[(4 + c) * 4 + b] + S[(8 + c) * 4 + b];
                dice_sum += (2.0 * inter + 1e-5) / (un + 1e-5);
            }
        double l_dice = 1.0 - dice_sum / 16.0;
        double l_ce = (S[48] + S[49] + S[50] + S[51]) / (4.0 * NV);
        double lb = 0.0;
        for (int cb = 0; cb < 12; ++cb) {
            int b = cb / 3, c = cb % 3 + 1;
            double cnt = S[(8 + c) * 4 + b];
            double s;
            if (cnt == 0.0)      s =  S[(4 + c) * 4 + b];   // sdf == +1 everywhere
            else if (cnt == NV)  s = -S[(4 + c) * 4 + b];   // sdf == -1 everywhere
            else                 s =  (double)bred[cb];
            lb += s / NV;
        }
        lb /= 12.0;
        out[0] = (float)(l_dice + l_ce + 0.01 * lb);
    }
}

extern "C" void kernel_launch(void* const* d_in, const int* in_sizes, int n_in,
                              void* d_out, int out_size, void* d_ws, size_t ws_size,
                              hipStream_t stream) {
    const float* preds   = (const float*)d_in[0];
    const int*   targets = (const int*)d_in[1];
    float* out = (float*)d_out;

    // workspace: bufA u16 (12.6 MB) | probsT bf16 (6.3 MB) | partials (~56 KB)
    unsigned short* bufA   = (unsigned short*)d_ws;
    unsigned short* probsT = bufA + (size_t)24 * NVOX;
    float* part_stats = (float*)(probsT + (size_t)12 * NVOX);
    float* part_bound = part_stats + 13 * 1024;

    kAx_stats_probs<<<512, 256, 0, stream>>>(preds, targets, probsT, part_stats);
    kB_edt12<<<GRID_B, 256, 0, stream>>>(targets, bufA);
    K2_edt3_sdf<<<GRID_K2, 512, 0, stream>>>(bufA, probsT, part_bound);
    K3_final<<<1, 1024, 0, stream>>>(part_stats, part_bound, out);
}

// Round 10
// 54.023 us; speedup vs baseline: 1.0824x; 1.0095x over previous
//
#include <hip/hip_runtime.h>
#include <math.h>

#define NVOX 262144   // 64^3
#define GRID_B 768    // EDT W+H blocks (b*192 + d*3 + cm)

// squared distance (u16, 0xFFFF acts as +inf) from lane w to nearest set bit
__device__ __forceinline__ unsigned short dist2_u16(unsigned long long mask, int w) {
    if (mask == 0ull) return 0xFFFFu;
    unsigned long long mr = mask >> w;          // bits k >= w
    unsigned long long ml = mask << (63 - w);   // bits k <= w
    int dr = mr ? __builtin_ctzll(mr) : 127;
    int dl = ml ? __builtin_clzll(ml) : 127;
    int dd = dr < dl ? dr : dl;
    return (unsigned short)(dd * dd);
}

// =====================================================================
// kB: EDT pass-1 (W, ballot) + pass-2 (H, early-exit) in u16 LDS tiles.
// 65535 acts as +inf (center candidate caps best; any real candidate
// <= 11907 wins). grid = 768 (b*192 + d*3 + cm), 256 thr.
// Writes bufA[combo + 12*v][h][d][w] (u16 squared dist).
// =====================================================================
__global__ __launch_bounds__(256) void kB_edt12(
    const int* __restrict__ targets, unsigned short* __restrict__ bufA) {
    __shared__ unsigned short tO[64 * 66];
    __shared__ unsigned short tI[64 * 66];
    int blk = blockIdx.x;
    int cm = blk % 3;
    int bd = blk / 3;            // b*64 + d
    int d = bd & 63, b = bd >> 6;
    int c = cm + 1;
    int t = threadIdx.x, lane = t & 63, wid = t >> 6;
    const int* tg = targets + (size_t)b * NVOX + (size_t)d * 4096;

    #pragma unroll
    for (int i = 0; i < 16; ++i) {
        int e = t + 256 * i;
        int h = wid + 4 * i;
        int tv = tg[e];
        unsigned long long mask = __ballot(tv == c);
        tO[h * 66 + lane] = dist2_u16(mask, lane);
        tI[h * 66 + lane] = dist2_u16(~mask, lane);
    }
    __syncthreads();

    // pass-2 along H: wave owns 16 cols w = wid*16+r; lane = h. Early-exit.
    for (int r = 0; r < 16; ++r) {
        int w = wid * 16 + r;
        {
            unsigned best = tO[lane * 66 + w];
            for (int dk = 1; dk < 64; ++dk) {
                unsigned d2 = (unsigned)(dk * dk);
                if (__all(d2 >= best)) break;
                int hl = lane - dk; hl = hl < 0 ? 0 : hl;
                int hr = lane + dk; hr = hr > 63 ? 63 : hr;
                unsigned ca = tO[hl * 66 + w] + d2;
                unsigned cb = tO[hr * 66 + w] + d2;
                ca = ca < cb ? ca : cb;
                best = best < ca ? best : ca;
            }
            tO[lane * 66 + w] = (unsigned short)best;   // lockstep: safe in-place
        }
        {
            unsigned best = tI[lane * 66 + w];
            for (int dk = 1; dk < 64; ++dk) {
                unsigned d2 = (unsigned)(dk * dk);
                if (__all(d2 >= best)) break;
                int hl = lane - dk; hl = hl < 0 ? 0 : hl;
                int hr = lane + dk; hr = hr > 63 ? 63 : hr;
                unsigned ca = tI[hl * 66 + w] + d2;
                unsigned cb = tI[hr * 66 + w] + d2;
                ca = ca < cb ? ca : cb;
                best = best < ca ? best : ca;
            }
            tI[lane * 66 + w] = (unsigned short)best;
        }
    }
    __syncthreads();

    int combo = b * 3 + cm;
    size_t oO = (size_t)combo * NVOX + (size_t)d * 64;
    size_t oI = (size_t)(combo + 12) * NVOX + (size_t)d * 64;
    #pragma unroll
    for (int i = 0; i < 16; ++i) {
        int h = wid + 4 * i;
        bufA[oO + (size_t)h * 4096 + lane] = tO[h * 66 + lane];
        bufA[oI + (size_t)h * 4096 + lane] = tI[h * 66 + lane];
    }
}

// =====================================================================
// K2big: ONE kernel for softmax stats + EDT pass-3 (D) + sdf*prob.
// grid = 256 (b*64 + h), 512 thr. Per block:
//  1. 6 bufA planes (3 combos x out/in) -> u16 LDS tiles [d][w] (pitch 66)
//  2. preds[b, 0..3, :, h, :] -> f32 softmax: probs c=1..3 in regs + 13
//     dice/CE partials (each volume covered once across its 64 h-blocks)
//  3. integer min-plus scan along D per column (exact; early-exit)
//  4. sdf = sqrt(dO)-sqrt(dI); accumulate sdf*prob per combo
// No probsT intermediate anywhere; probs at full f32 accuracy.
// =====================================================================
__global__ __launch_bounds__(512) void K2_big(
    const float* __restrict__ preds, const int* __restrict__ targets,
    unsigned short* __restrict__ bufA,
    float* __restrict__ part_stats, float* __restrict__ part_bound) {
    __shared__ unsigned short tile[6][64 * 66];   // 50.7 KB
    __shared__ float sred[8][16];
    __shared__ float bsum[8][3];
    int blk = blockIdx.x;
    int b = blk >> 6, h = blk & 63;
    int t = threadIdx.x, lane = t & 63, wid = t >> 6;

    // ---- 1. load 6 dist planes into LDS (uint4 = 8 u16 per thread/plane) ----
    int e0 = 8 * t, d0 = e0 >> 6, w0 = e0 & 63;
    #pragma unroll
    for (int p = 0; p < 6; ++p) {
        int cm = p >> 1, v = p & 1;
        const unsigned short* src =
            bufA + (size_t)(b * 3 + cm + 12 * v) * NVOX + (size_t)h * 4096 + e0;
        uint4 u = *(const uint4*)src;
        unsigned* dst32 = (unsigned*)&tile[p][d0 * 66 + w0];   // w0 % 8 == 0 -> 4B aligned
        dst32[0] = u.x; dst32[1] = u.y; dst32[2] = u.z; dst32[3] = u.w;
    }

    // ---- 2. preds + targets, softmax, stats, probs in regs ----
    size_t vbase = (size_t)d0 * 4096 + (size_t)h * 64 + w0;
    const float* pp = preds + (size_t)(b * 4) * NVOX + vbase;
    float4 f[4][2];
    #pragma unroll
    for (int c = 0; c < 4; ++c) {
        f[c][0] = *(const float4*)(pp + (size_t)c * NVOX);
        f[c][1] = *(const float4*)(pp + (size_t)c * NVOX + 4);
    }
    const int* tp = targets + (size_t)b * NVOX + vbase;
    int4 tg0 = *(const int4*)(tp);
    int4 tg1 = *(const int4*)(tp + 4);

    const float L2E = 1.4426950408889634f;
    const float LN2 = 0.6931471805599453f;
    float q[13];
    #pragma unroll
    for (int k = 0; k < 13; ++k) q[k] = 0.0f;
    float pr[3][8];

    #pragma unroll
    for (int j = 0; j < 8; ++j) {
        float a0 = (&f[0][j >> 2].x)[j & 3];
        float a1 = (&f[1][j >> 2].x)[j & 3];
        float a2 = (&f[2][j >> 2].x)[j & 3];
        float a3 = (&f[3][j >> 2].x)[j & 3];
        int tv = (j < 4) ? (&tg0.x)[j] : (&tg1.x)[j - 4];
        float m  = fmaxf(fmaxf(a0, a1), fmaxf(a2, a3));
        float e0_ = exp2f((a0 - m) * L2E);
        float e1_ = exp2f((a1 - m) * L2E);
        float e2_ = exp2f((a2 - m) * L2E);
        float e3_ = exp2f((a3 - m) * L2E);
        float ssum = e0_ + e1_ + e2_ + e3_;
        float inv  = __builtin_amdgcn_rcpf(ssum);
        float p0 = e0_ * inv, p1 = e1_ * inv, p2 = e2_ * inv, p3 = e3_ * inv;
        float xt = (tv == 0) ? a0 : (tv == 1) ? a1 : (tv == 2) ? a2 : a3;
        q[12] += (m - xt) + log2f(ssum) * LN2;
        q[4] += p0; q[5] += p1; q[6] += p2; q[7] += p3;
        if (tv == 0)      { q[0] += p0; q[8]  += 1.0f; }
        else if (tv == 1) { q[1] += p1; q[9]  += 1.0f; }
        else if (tv == 2) { q[2] += p2; q[10] += 1.0f; }
        else              { q[3] += p3; q[11] += 1.0f; }
        pr[0][j] = p1; pr[1][j] = p2; pr[2][j] = p3;
    }
    __syncthreads();   // tiles complete

    // ---- 3. integer min-plus scan along D (lane = d), 48 cols per wave ----
    for (int job = wid; job < 384; job += 8) {
        int p = job >> 6, w = job & 63;
        unsigned short* T = tile[p];
        unsigned best = T[lane * 66 + w];
        for (int dk = 1; dk < 64; ++dk) {
            unsigned d2 = (unsigned)(dk * dk);
            if (__all(d2 >= best)) break;
            int dl = lane - dk; dl = dl < 0 ? 0 : dl;
            int dr = lane + dk; dr = dr > 63 ? 63 : dr;
            unsigned ca = T[dl * 66 + w] + d2;
            unsigned cb = T[dr * 66 + w] + d2;
            ca = ca < cb ? ca : cb;
            best = best < ca ? best : ca;
        }
        T[lane * 66 + w] = (unsigned short)best;   // lockstep: safe in-place
    }
    __syncthreads();

    // ---- 4. sdf * prob per combo ----
    float accb[3] = {0.0f, 0.0f, 0.0f};
    #pragma unroll
    for (int j = 0; j < 8; ++j) {
        int idx = d0 * 66 + w0 + j;
        #pragma unroll
        for (int cm = 0; cm < 3; ++cm) {
            float dO = (float)tile[2 * cm][idx];
            float dI = (float)tile[2 * cm + 1][idx];
            float sdf = sqrtf(dO) - sqrtf(dI);
            accb[cm] += sdf * pr[cm][j];
        }
    }

    // ---- reductions ----
    #pragma unroll
    for (int k = 0; k < 13; ++k) {
        float x = q[k];
        #pragma unroll
        for (int o = 32; o > 0; o >>= 1) x += __shfl_down(x, o);
        if (lane == 0) sred[wid][k] = x;
    }
    #pragma unroll
    for (int cm = 0; cm < 3; ++cm) {
        float x = accb[cm];
        #pragma unroll
        for (int o = 32; o > 0; o >>= 1) x += __shfl_down(x, o);
        if (lane == 0) bsum[wid][cm] = x;
    }
    __syncthreads();
    if (t < 13) {
        float s = 0.0f;
        #pragma unroll
        for (int ww = 0; ww < 8; ++ww) s += sred[ww][t];
        part_stats[t * 256 + blk] = s;
    }
    if (t >= 64 && t < 67) {
        int cm = t - 64;
        float s = 0.0f;
        #pragma unroll
        for (int ww = 0; ww < 8; ++ww) s += bsum[ww][cm];
        part_bound[(b * 3 + cm) * 64 + h] = s;
    }
}

// =====================================================================
// K3: single block (16 waves). Waves 0-3: stats rows (256 entries);
// waves 4-15: bound rows (768 entries). f64 combine + guards.
// =====================================================================
__global__ __launch_bounds__(1024) void K3_final(
    const float* __restrict__ part_stats, const float* __restrict__ part_bound,
    float* __restrict__ out) {
    __shared__ float sred[52];    // [k][b] = k*4+b
    __shared__ float bred[12];
    __shared__ double S[52];
    int t = threadIdx.x, lane = t & 63, wid = t >> 6;

    if (wid < 4) {                // t < 256: entry = b*64 + h, b = wid
        float v[13];
        #pragma unroll
        for (int k = 0; k < 13; ++k) v[k] = part_stats[k * 256 + t];
        #pragma unroll
        for (int k = 0; k < 13; ++k) {
            float x = v[k];
            #pragma unroll
            for (int o = 32; o > 0; o >>= 1) x += __shfl_down(x, o);
            if (lane == 0) sred[k * 4 + wid] = x;
        }
    } else {                      // waves 4..15 -> combo = wid-4
        float bv = part_bound[(wid - 4) * 64 + lane];
        #pragma unroll
        for (int o = 32; o > 0; o >>= 1) bv += __shfl_down(bv, o);
        if (lane == 0) bred[wid - 4] = bv;
    }
    __syncthreads();
    if (t < 52) S[t] = (double)sred[t];
    __syncthreads();
    if (t == 0) {
        const double NV = (double)NVOX;
        double dice_sum = 0.0;
        for (int b = 0; b < 4; ++b)
            for (int c = 0; c < 4; ++c) {
                double inter = S[c * 4 + b];
                double un    = S[(4 + c) * 4 + b] + S[(8 + c) * 4 + b];
                dice_sum += (2.0 * inter + 1e-5) / (un + 1e-5);
            }
        double l_dice = 1.0 - dice_sum / 16.0;
        double l_ce = (S[48] + S[49] + S[50] + S[51]) / (4.0 * NV);
        double lb = 0.0;
        for (int cb = 0; cb < 12; ++cb) {
            int b = cb / 3, c = cb % 3 + 1;
            double cnt = S[(8 + c) * 4 + b];
            double s;
            if (cnt == 0.0)      s =  S[(4 + c) * 4 + b];   // sdf == +1 everywhere
            else if (cnt == NV)  s = -S[(4 + c) * 4 + b];   // sdf == -1 everywhere
            else                 s =  (double)bred[cb];
            lb += s / NV;
        }
        lb /= 12.0;
        out[0] = (float)(l_dice + l_ce + 0.01 * lb);
    }
}

extern "C" void kernel_launch(void* const* d_in, const int* in_sizes, int n_in,
                              void* d_out, int out_size, void* d_ws, size_t ws_size,
                              hipStream_t stream) {
    const float* preds   = (const float*)d_in[0];
    const int*   targets = (const int*)d_in[1];
    float* out = (float*)d_out;

    // workspace: bufA u16 (12.6 MB) | partials (~4 KB)
    unsigned short* bufA = (unsigned short*)d_ws;
    float* part_stats = (float*)(bufA + (size_t)24 * NVOX);
    float* part_bound = part_stats + 13 * 256;

    kB_edt12<<<GRID_B, 256, 0, stream>>>(targets, bufA);
    K2_big<<<256, 512, 0, stream>>>(preds, targets, bufA, part_stats, part_bound);
    K3_final<<<1, 1024, 0, stream>>>(part_stats, part_bound, out);
}

// Round 11
// 53.930 us; speedup vs baseline: 1.0843x; 1.0017x over previous
//
#include <hip/hip_runtime.h>
#include <math.h>

#define NVOX 262144   // 64^3
#define GRID_B 768    // EDT W+H blocks (b*192 + d*3 + cm)

typedef float f32x4 __attribute__((ext_vector_type(4)));

// squared distance (u16, 0xFFFF acts as +inf) from lane w to nearest set bit
__device__ __forceinline__ unsigned short dist2_u16(unsigned long long mask, int w) {
    if (mask == 0ull) return 0xFFFFu;
    unsigned long long mr = mask >> w;          // bits k >= w
    unsigned long long ml = mask << (63 - w);   // bits k <= w
    int dr = mr ? __builtin_ctzll(mr) : 127;
    int dl = ml ? __builtin_clzll(ml) : 127;
    int dd = dr < dl ? dr : dl;
    return (unsigned short)(dd * dd);
}

// =====================================================================
// kB: EDT pass-1 (W, ballot) + pass-2 (H, early-exit) in u16 LDS tiles.
// 65535 acts as +inf. grid = 768 (b*192 + d*3 + cm), 256 thr.
// Writes bufA[combo + 12*v][h][d][w] (u16 squared dist).
// =====================================================================
__global__ __launch_bounds__(256) void kB_edt12(
    const int* __restrict__ targets, unsigned short* __restrict__ bufA) {
    __shared__ unsigned short tO[64 * 66];
    __shared__ unsigned short tI[64 * 66];
    int blk = blockIdx.x;
    int cm = blk % 3;
    int bd = blk / 3;            // b*64 + d
    int d = bd & 63, b = bd >> 6;
    int c = cm + 1;
    int t = threadIdx.x, lane = t & 63, wid = t >> 6;
    const int* tg = targets + (size_t)b * NVOX + (size_t)d * 4096;

    #pragma unroll
    for (int i = 0; i < 16; ++i) {
        int e = t + 256 * i;
        int h = wid + 4 * i;
        int tv = tg[e];
        unsigned long long mask = __ballot(tv == c);
        tO[h * 66 + lane] = dist2_u16(mask, lane);
        tI[h * 66 + lane] = dist2_u16(~mask, lane);
    }
    __syncthreads();

    // pass-2 along H: wave owns 16 cols w = wid*16+r; lane = h. Early-exit.
    for (int r = 0; r < 16; ++r) {
        int w = wid * 16 + r;
        {
            unsigned best = tO[lane * 66 + w];
            for (int dk = 1; dk < 64; ++dk) {
                unsigned d2 = (unsigned)(dk * dk);
                if (__all(d2 >= best)) break;
                int hl = lane - dk; hl = hl < 0 ? 0 : hl;
                int hr = lane + dk; hr = hr > 63 ? 63 : hr;
                unsigned ca = tO[hl * 66 + w] + d2;
                unsigned cb = tO[hr * 66 + w] + d2;
                ca = ca < cb ? ca : cb;
                best = best < ca ? best : ca;
            }
            tO[lane * 66 + w] = (unsigned short)best;   // lockstep: safe in-place
        }
        {
            unsigned best = tI[lane * 66 + w];
            for (int dk = 1; dk < 64; ++dk) {
                unsigned d2 = (unsigned)(dk * dk);
                if (__all(d2 >= best)) break;
                int hl = lane - dk; hl = hl < 0 ? 0 : hl;
                int hr = lane + dk; hr = hr > 63 ? 63 : hr;
                unsigned ca = tI[hl * 66 + w] + d2;
                unsigned cb = tI[hr * 66 + w] + d2;
                ca = ca < cb ? ca : cb;
                best = best < ca ? best : ca;
            }
            tI[lane * 66 + w] = (unsigned short)best;
        }
    }
    __syncthreads();

    int combo = b * 3 + cm;
    size_t oO = (size_t)combo * NVOX + (size_t)d * 64;
    size_t oI = (size_t)(combo + 12) * NVOX + (size_t)d * 64;
    #pragma unroll
    for (int i = 0; i < 16; ++i) {
        int h = wid + 4 * i;
        bufA[oO + (size_t)h * 4096 + lane] = tO[h * 66 + lane];
        bufA[oI + (size_t)h * 4096 + lane] = tI[h * 66 + lane];
    }
}

// =====================================================================
// K2big v2: softmax stats + EDT pass-3 (D) + sdf*prob, w-split for
// occupancy. grid = 512 (b*128 + h*2 + wh), 512 thr, 26 KB LDS
// -> 2 blocks/CU, 16 waves/CU (was 1 block / 8 waves: latency-starved).
// Each block: half-plane w' in [wh*32, wh*32+32), all 64 d.
// preds loads are non-temporal (single-use stream; keep L2 for bufA).
// =====================================================================
__global__ __launch_bounds__(512) void K2_big(
    const float* __restrict__ preds, const int* __restrict__ targets,
    unsigned short* __restrict__ bufA,
    float* __restrict__ part_stats, float* __restrict__ part_bound) {
    __shared__ unsigned short tile[6][64 * 34];   // pitch 34: bank-stride 17 -> 2-way (free)
    __shared__ float sred[8][16];
    __shared__ float bsum[8][3];
    int blk = blockIdx.x;
    int b = blk >> 7, rem = blk & 127;
    int h = rem >> 1, wh = rem & 1;
    int t = threadIdx.x, lane = t & 63, wid = t >> 6;

    int e = 4 * t;                     // [0,2048): element in half-plane
    int d0 = e >> 5, w0 = e & 31;      // d row, w' offset (mult of 4)

    // ---- issue preds + targets loads (non-temporal for preds) ----
    size_t vbase = (size_t)d0 * 4096 + (size_t)h * 64 + wh * 32 + w0;
    const float* pp = preds + (size_t)(b * 4) * NVOX + vbase;
    f32x4 f0 = __builtin_nontemporal_load((const f32x4*)(pp));
    f32x4 f1 = __builtin_nontemporal_load((const f32x4*)(pp + NVOX));
    f32x4 f2 = __builtin_nontemporal_load((const f32x4*)(pp + 2 * NVOX));
    f32x4 f3 = __builtin_nontemporal_load((const f32x4*)(pp + 3 * NVOX));
    int4 tg4 = *(const int4*)(targets + (size_t)b * NVOX + vbase);

    // ---- load 6 dist half-planes into LDS (uint2 = 4 u16 per thread) ----
    size_t poffg = (size_t)h * 4096 + (size_t)d0 * 64 + wh * 32 + w0;
    #pragma unroll
    for (int p = 0; p < 6; ++p) {
        int cm = p >> 1, v = p & 1;
        const unsigned short* src = bufA + (size_t)(b * 3 + cm + 12 * v) * NVOX + poffg;
        uint2 u = *(const uint2*)src;
        unsigned* dst32 = (unsigned*)&tile[p][d0 * 34 + w0];   // w0%4==0 -> 8B aligned
        dst32[0] = u.x; dst32[1] = u.y;
    }

    // ---- softmax + stats + probs (4 voxels) ----
    const float L2E = 1.4426950408889634f;
    const float LN2 = 0.6931471805599453f;
    float q[13];
    #pragma unroll
    for (int k = 0; k < 13; ++k) q[k] = 0.0f;
    float pr[3][4];

    #pragma unroll
    for (int j = 0; j < 4; ++j) {
        float a0 = f0[j], a1 = f1[j], a2 = f2[j], a3 = f3[j];
        int tv = (&tg4.x)[j];
        float m  = fmaxf(fmaxf(a0, a1), fmaxf(a2, a3));
        float e0_ = exp2f((a0 - m) * L2E);
        float e1_ = exp2f((a1 - m) * L2E);
        float e2_ = exp2f((a2 - m) * L2E);
        float e3_ = exp2f((a3 - m) * L2E);
        float ssum = e0_ + e1_ + e2_ + e3_;
        float inv  = __builtin_amdgcn_rcpf(ssum);
        float p0 = e0_ * inv, p1 = e1_ * inv, p2 = e2_ * inv, p3 = e3_ * inv;
        float xt = (tv == 0) ? a0 : (tv == 1) ? a1 : (tv == 2) ? a2 : a3;
        q[12] += (m - xt) + log2f(ssum) * LN2;
        q[4] += p0; q[5] += p1; q[6] += p2; q[7] += p3;
        if (tv == 0)      { q[0] += p0; q[8]  += 1.0f; }
        else if (tv == 1) { q[1] += p1; q[9]  += 1.0f; }
        else if (tv == 2) { q[2] += p2; q[10] += 1.0f; }
        else              { q[3] += p3; q[11] += 1.0f; }
        pr[0][j] = p1; pr[1][j] = p2; pr[2][j] = p3;
    }
    __syncthreads();   // tiles complete

    // ---- integer min-plus scan along D (lane = d); 6 planes x 32 cols ----
    for (int job = wid; job < 192; job += 8) {
        int p = job >> 5, w = job & 31;
        unsigned short* T = tile[p];
        unsigned best = T[lane * 34 + w];
        for (int dk = 1; dk < 64; ++dk) {
            unsigned d2 = (unsigned)(dk * dk);
            if (__all(d2 >= best)) break;
            int dl = lane - dk; dl = dl < 0 ? 0 : dl;
            int dr = lane + dk; dr = dr > 63 ? 63 : dr;
            unsigned ca = T[dl * 34 + w] + d2;
            unsigned cb = T[dr * 34 + w] + d2;
            ca = ca < cb ? ca : cb;
            best = best < ca ? best : ca;
        }
        T[lane * 34 + w] = (unsigned short)best;   // lockstep: safe in-place
    }
    __syncthreads();

    // ---- sdf * prob per combo ----
    float accb[3] = {0.0f, 0.0f, 0.0f};
    #pragma unroll
    for (int j = 0; j < 4; ++j) {
        int idx = d0 * 34 + w0 + j;
        #pragma unroll
        for (int cm = 0; cm < 3; ++cm) {
            float dO = (float)tile[2 * cm][idx];
            float dI = (float)tile[2 * cm + 1][idx];
            float sdf = sqrtf(dO) - sqrtf(dI);
            accb[cm] += sdf * pr[cm][j];
        }
    }

    // ---- reductions ----
    #pragma unroll
    for (int k = 0; k < 13; ++k) {
        float x = q[k];
        #pragma unroll
        for (int o = 32; o > 0; o >>= 1) x += __shfl_down(x, o);
        if (lane == 0) sred[wid][k] = x;
    }
    #pragma unroll
    for (int cm = 0; cm < 3; ++cm) {
        float x = accb[cm];
        #pragma unroll
        for (int o = 32; o > 0; o >>= 1) x += __shfl_down(x, o);
        if (lane == 0) bsum[wid][cm] = x;
    }
    __syncthreads();
    if (t < 13) {
        float s = 0.0f;
        #pragma unroll
        for (int ww = 0; ww < 8; ++ww) s += sred[ww][t];
        part_stats[t * 512 + blk] = s;
    }
    if (t >= 64 && t < 67) {
        int cm = t - 64;
        float s = 0.0f;
        #pragma unroll
        for (int ww = 0; ww < 8; ++ww) s += bsum[ww][cm];
        part_bound[(b * 3 + cm) * 128 + rem] = s;
    }
}

// =====================================================================
// K3: single block, 1024 thr. Waves 0-7: stats rows (512 entries,
// entry = b*128 + i). Waves 8-15: bound rows (12 combos x 128).
// =====================================================================
__global__ __launch_bounds__(1024) void K3_final(
    const float* __restrict__ part_stats, const float* __restrict__ part_bound,
    float* __restrict__ out) {
    __shared__ float sredf[13 * 8];
    __shared__ float bred[12];
    __shared__ double S[52];
    int t = threadIdx.x, lane = t & 63, wid = t >> 6;

    if (t < 512) {                // waves 0-7; wave w covers entries w*64..w*64+63
        float v[13];
        #pragma unroll
        for (int k = 0; k < 13; ++k) v[k] = part_stats[k * 512 + t];
        #pragma unroll
        for (int k = 0; k < 13; ++k) {
            float x = v[k];
            #pragma unroll
            for (int o = 32; o > 0; o >>= 1) x += __shfl_down(x, o);
            if (lane == 0) sredf[k * 8 + wid] = x;
        }
    } else {                      // waves 8-15: combos
        int m = wid - 8;
        float bv = part_bound[m * 128 + lane] + part_bound[m * 128 + 64 + lane];
        #pragma unroll
        for (int o = 32; o > 0; o >>= 1) bv += __shfl_down(bv, o);
        if (lane == 0) bred[m] = bv;
        if (m < 4) {
            int m2 = 8 + m;
            float b2 = part_bound[m2 * 128 + lane] + part_bound[m2 * 128 + 64 + lane];
            #pragma unroll
            for (int o = 32; o > 0; o >>= 1) b2 += __shfl_down(b2, o);
            if (lane == 0) bred[m2] = b2;
        }
    }
    __syncthreads();
    if (t < 52) {   // k = t>>2, b = t&3; wave pair 2b,2b+1 covers batch b
        int k = t >> 2, b = t & 3;
        S[k * 4 + b] = (double)sredf[k * 8 + 2 * b] + (double)sredf[k * 8 + 2 * b + 1];
    }
    __syncthreads();
    if (t == 0) {
        const double NV = (double)NVOX;
        double dice_sum = 0.0;
        for (int b = 0; b < 4; ++b)
            for (int c = 0; c < 4; ++c) {
                double inter = S[c * 4 + b];
                double un    = S[(4 + c) * 4 + b] + S[(8 + c) * 4 + b];
                dice_sum += (2.0 * inter + 1e-5) / (un + 1e-5);
            }
        double l_dice = 1.0 - dice_sum / 16.0;
        double l_ce = (S[48] + S[49] + S[50] + S[51]) / (4.0 * NV);
        double lb = 0.0;
        for (int cb = 0; cb < 12; ++cb) {
            int b = cb / 3, c = cb % 3 + 1;
            double cnt = S[(8 + c) * 4 + b];
            double s;
            if (cnt == 0.0)      s =  S[(4 + c) * 4 + b];   // sdf == +1 everywhere
            else if (cnt == NV)  s = -S[(4 + c) * 4 + b];   // sdf == -1 everywhere
            else                 s =  (double)bred[cb];
            lb += s / NV;
        }
        lb /= 12.0;
        out[0] = (float)(l_dice + l_ce + 0.01 * lb);
    }
}

extern "C" void kernel_launch(void* const* d_in, const int* in_sizes, int n_in,
                              void* d_out, int out_size, void* d_ws, size_t ws_size,
                              hipStream_t stream) {
    const float* preds   = (const float*)d_in[0];
    const int*   targets = (const int*)d_in[1];
    float* out = (float*)d_out;

    // workspace: bufA u16 (12.6 MB) | part_stats 13*512 f32 | part_bound 1536 f32
    unsigned short* bufA = (unsigned short*)d_ws;
    float* part_stats = (float*)(bufA + (size_t)24 * NVOX);
    float* part_bound = part_stats + 13 * 512;

    kB_edt12<<<GRID_B, 256, 0, stream>>>(targets, bufA);
    K2_big<<<512, 512, 0, stream>>>(preds, targets, bufA, part_stats, part_bound);
    K3_final<<<1, 1024, 0, stream>>>(part_stats, part_bound, out);
}

// Round 13
// 49.365 us; speedup vs baseline: 1.1845x; 1.0925x over previous
//
#include <hip/hip_runtime.h>
#include <hip/hip_bf16.h>
#include <math.h>

#define NVOX 262144   // 64^3

// ---- helpers ----
__device__ __forceinline__ unsigned short f2bf(float x) {
    __hip_bfloat16 h = __float2bfloat16(x);
    return *reinterpret_cast<unsigned short*>(&h);
}
__device__ __forceinline__ float bf2f(unsigned short u) {
    __hip_bfloat16 h = *reinterpret_cast<__hip_bfloat16*>(&u);
    return __bfloat162float(h);
}
// squared distance (u16, 0xFFFF acts as +inf) from lane w to nearest set bit
__device__ __forceinline__ unsigned short dist2_u16(unsigned long long mask, int w) {
    if (mask == 0ull) return 0xFFFFu;
    unsigned long long mr = mask >> w;          // bits k >= w
    unsigned long long ml = mask << (63 - w);   // bits k <= w
    int dr = mr ? __builtin_ctzll(mr) : 127;
    int dl = ml ? __builtin_clzll(ml) : 127;
    int dd = dr < dl ? dr : dl;
    return (unsigned short)(dd * dd);
}

// =====================================================================
// kWarm: pure-stream touch of preds (16.8 MB) + targets (4 MB) to pull
// them into Infinity Cache (memory-side; survives dispatch boundaries).
// 2048 blocks x 256 thr, 2 float4/thread, perfectly coalesced.
// Sink defeats DCE (one store per wave into scratch).
// =====================================================================
__global__ __launch_bounds__(256) void kWarm(
    const float* __restrict__ preds, const int* __restrict__ targets,
    float* __restrict__ sink) {
    int tid = blockIdx.x * 256 + threadIdx.x;          // [0, 524288)
    const float4* p4 = (const float4*)preds;           // 1,048,576 float4s
    float4 a = p4[tid];
    float4 b = p4[tid + 524288];
    float acc = a.x + a.y + a.z + a.w + b.x + b.y + b.z + b.w;
    if (tid < 262144) {                                // 1,048,576 ints / 4
        int4 tv = ((const int4*)targets)[tid];
        acc += (float)(tv.x + tv.y + tv.z + tv.w);
    }
    #pragma unroll
    for (int o = 32; o > 0; o >>= 1) acc += __shfl_down(acc, o);
    if ((threadIdx.x & 63) == 0) sink[blockIdx.x * 4 + (threadIdx.x >> 6)] = acc;
}

// =====================================================================
// K1_fused (R6 structure): blocks [0,1024): streaming softmax stats +
// bf16 probsT (native exp2/log2/rcp). Blocks [1024,1792): ballot EDT
// pass-1 (W) + early-exit pass-2 (H) in u16 LDS tiles -> bufA.
// Layouts: probsT[combo][h][d][w] bf16; bufA[combo+12v][h][d][w] u16.
// =====================================================================
__global__ __launch_bounds__(256) void K1_fused(
    const float* __restrict__ preds, const int* __restrict__ targets,
    unsigned short* __restrict__ bufA, unsigned short* __restrict__ probsT,
    float* __restrict__ part_stats) {
    __shared__ unsigned short tO[64 * 66];
    __shared__ unsigned short tI[64 * 66];
    __shared__ float sred[4 * 13];
    int bid = blockIdx.x;
    int t = threadIdx.x, lane = t & 63, wid = t >> 6;

    if (bid < 1024) {
        // ---------- path A: streaming stats + probs ----------
        int b = bid >> 8, seg = bid & 255;
        size_t vbase = (size_t)seg * 1024 + 4 * t;
        const float* p = preds + (size_t)(b * 4) * NVOX + vbase;
        float4 x0 = *(const float4*)(p);
        float4 x1 = *(const float4*)(p + NVOX);
        float4 x2 = *(const float4*)(p + 2 * NVOX);
        float4 x3 = *(const float4*)(p + 3 * NVOX);
        int4 tv4 = *(const int4*)(targets + (size_t)b * NVOX + vbase);

        const float L2E = 1.4426950408889634f;
        const float LN2 = 0.6931471805599453f;
        float q[13];
        #pragma unroll
        for (int k = 0; k < 13; ++k) q[k] = 0.0f;
        unsigned short pb[3][4];

        #pragma unroll
        for (int j = 0; j < 4; ++j) {
            float a0 = (&x0.x)[j], a1 = (&x1.x)[j], a2 = (&x2.x)[j], a3 = (&x3.x)[j];
            int tv = (&tv4.x)[j];
            float m  = fmaxf(fmaxf(a0, a1), fmaxf(a2, a3));
            float e0 = exp2f((a0 - m) * L2E);
            float e1 = exp2f((a1 - m) * L2E);
            float e2 = exp2f((a2 - m) * L2E);
            float e3 = exp2f((a3 - m) * L2E);
            float ssum = e0 + e1 + e2 + e3;
            float inv  = __builtin_amdgcn_rcpf(ssum);
            float p0 = e0 * inv, p1 = e1 * inv, p2 = e2 * inv, p3 = e3 * inv;
            float xt = (tv == 0) ? a0 : (tv == 1) ? a1 : (tv == 2) ? a2 : a3;
            q[12] += (m - xt) + log2f(ssum) * LN2;
            q[4] += p0; q[5] += p1; q[6] += p2; q[7] += p3;
            if (tv == 0)      { q[0] += p0; q[8]  += 1.0f; }
            else if (tv == 1) { q[1] += p1; q[9]  += 1.0f; }
            else if (tv == 2) { q[2] += p2; q[10] += 1.0f; }
            else              { q[3] += p3; q[11] += 1.0f; }
            pb[0][j] = f2bf(p1); pb[1][j] = f2bf(p2); pb[2][j] = f2bf(p3);
        }

        int v0 = (int)vbase;
        int d = v0 >> 12, h = (v0 >> 6) & 63, w0 = v0 & 63;
        size_t poff = (size_t)h * 4096 + d * 64 + w0;
        #pragma unroll
        for (int c = 0; c < 3; ++c) {
            ushort4 u = make_ushort4(pb[c][0], pb[c][1], pb[c][2], pb[c][3]);
            *(ushort4*)(probsT + (size_t)(b * 3 + c) * NVOX + poff) = u;
        }

        #pragma unroll
        for (int k = 0; k < 13; ++k) {
            float x = q[k];
            #pragma unroll
            for (int o = 32; o > 0; o >>= 1) x += __shfl_down(x, o);
            if (lane == 0) sred[wid * 13 + k] = x;
        }
        __syncthreads();
        if (t < 13) {
            float s = sred[t] + sred[13 + t] + sred[26 + t] + sred[39 + t];
            part_stats[t * 1024 + bid] = s;
        }
    } else {
        // ---------- path B: EDT pass-1 (W, ballot) + pass-2 (H, early-exit) ----------
        int blk = bid - 1024;
        int cm = blk % 3;
        int bd = blk / 3;            // b*64 + d
        int d = bd & 63, b = bd >> 6;
        int c = cm + 1;
        const int* tg = targets + (size_t)b * NVOX + (size_t)d * 4096;

        #pragma unroll
        for (int i = 0; i < 16; ++i) {
            int e = t + 256 * i;
            int h = wid + 4 * i;
            int tv = tg[e];
            unsigned long long mask = __ballot(tv == c);
            tO[h * 66 + lane] = dist2_u16(mask, lane);
            tI[h * 66 + lane] = dist2_u16(~mask, lane);
        }
        __syncthreads();

        // pass-2 along H: wave owns 16 cols w = wid*16+r; lane = h. Early-exit.
        for (int r = 0; r < 16; ++r) {
            int w = wid * 16 + r;
            {
                unsigned best = tO[lane * 66 + w];
                for (int dk = 1; dk < 64; ++dk) {
                    unsigned d2 = (unsigned)(dk * dk);
                    if (__all(d2 >= best)) break;
                    int hl = lane - dk; hl = hl < 0 ? 0 : hl;
                    int hr = lane + dk; hr = hr > 63 ? 63 : hr;
                    unsigned ca = tO[hl * 66 + w] + d2;
                    unsigned cb = tO[hr * 66 + w] + d2;
                    ca = ca < cb ? ca : cb;
                    best = best < ca ? best : ca;
                }
                tO[lane * 66 + w] = (unsigned short)best;   // lockstep: safe in-place
            }
            {
                unsigned best = tI[lane * 66 + w];
                for (int dk = 1; dk < 64; ++dk) {
                    unsigned d2 = (unsigned)(dk * dk);
                    if (__all(d2 >= best)) break;
                    int hl = lane - dk; hl = hl < 0 ? 0 : hl;
                    int hr = lane + dk; hr = hr > 63 ? 63 : hr;
                    unsigned ca = tI[hl * 66 + w] + d2;
                    unsigned cb = tI[hr * 66 + w] + d2;
                    ca = ca < cb ? ca : cb;
                    best = best < ca ? best : ca;
                }
                tI[lane * 66 + w] = (unsigned short)best;
            }
        }
        __syncthreads();

        int combo = b * 3 + cm;
        size_t oO = (size_t)combo * NVOX + (size_t)d * 64;
        size_t oI = (size_t)(combo + 12) * NVOX + (size_t)d * 64;
        #pragma unroll
        for (int i = 0; i < 16; ++i) {
            int h = wid + 4 * i;
            bufA[oO + (size_t)h * 4096 + lane] = tO[h * 66 + lane];
            bufA[oI + (size_t)h * 4096 + lane] = tI[h * 66 + lane];
        }
    }
}

// =====================================================================
// K2: EDT pass-3 (D, early-exit) + sdf*prob reduce -> one float per block.
// grid = 768 (combo*64 + h), 512 thr. 65535-as-inf.
// =====================================================================
__global__ __launch_bounds__(512) void K2_edt3_sdf(
    const unsigned short* __restrict__ bufA, const unsigned short* __restrict__ probsT,
    float* __restrict__ part_bound) {
    __shared__ float pl[2][64 * 65];
    __shared__ float sredb[8];
    int blk = blockIdx.x;
    int combo = blk >> 6, h = blk & 63;
    int t = threadIdx.x, lane = t & 63, wid = t >> 6;

    for (int v = 0; v < 2; ++v) {
        const unsigned short* src = bufA + (size_t)(combo + 12 * v) * NVOX + (size_t)h * 4096;
        #pragma unroll
        for (int i = 0; i < 8; ++i) {
            int e = t + 512 * i;                     // e = d*64 + w
            pl[v][e + (e >> 6)] = (float)src[e];     // lds[d*65+w]
        }
    }
    __syncthreads();

    // pass along D: wave owns cols w = wid*8+r; lane = d. Early-exit.
    for (int v = 0; v < 2; ++v) {
        for (int r = 0; r < 8; ++r) {
            int w = wid * 8 + r;
            float* col = &pl[v][w];
            float best = col[lane * 65];
            for (int dk = 1; dk < 64; ++dk) {
                float d2 = (float)(dk * dk);
                if (__all(d2 >= best)) break;
                int dl = lane - dk; dl = dl < 0 ? 0 : dl;
                int dr = lane + dk; dr = dr > 63 ? 63 : dr;
                best = fminf(fminf(best, col[dl * 65] + d2), col[dr * 65] + d2);
            }
            col[lane * 65] = best;
        }
    }
    __syncthreads();

    const unsigned short* pp = probsT + (size_t)combo * NVOX + (size_t)h * 4096;
    float acc = 0.0f;
    #pragma unroll
    for (int i = 0; i < 8; ++i) {
        int e = t + 512 * i;
        int li = e + (e >> 6);
        float sdf = sqrtf(pl[0][li]) - sqrtf(pl[1][li]);
        acc += sdf * bf2f(pp[e]);
    }
    #pragma unroll
    for (int o = 32; o > 0; o >>= 1) acc += __shfl_down(acc, o);
    if (lane == 0) sredb[wid] = acc;
    __syncthreads();
    if (t == 0) {
        float s = 0.0f;
        for (int j = 0; j < 8; ++j) s += sredb[j];
        part_bound[blk] = s;
    }
}

// =====================================================================
// K3: single block; loads up-front, shfl/LDS reduce, f64 combine + guards.
// part_stats rows 1024 wide (256 blocks per batch; b = entry>>8).
// =====================================================================
__global__ __launch_bounds__(1024) void K3_final(
    const float* __restrict__ part_stats, const float* __restrict__ part_bound,
    float* __restrict__ out) {
    __shared__ float sred[13 * 16];
    __shared__ float bred[12];
    __shared__ double S[52];
    int t = threadIdx.x, lane = t & 63, wid = t >> 6;

    float v[13];
    #pragma unroll
    for (int k = 0; k < 13; ++k) v[k] = part_stats[k * 1024 + t];
    float bv = (wid < 12) ? part_bound[wid * 64 + lane] : 0.0f;

    #pragma unroll
    for (int k = 0; k < 13; ++k) {
        float x = v[k];
        #pragma unroll
        for (int o = 32; o > 0; o >>= 1) x += __shfl_down(x, o);
        if (lane == 0) sred[k * 16 + wid] = x;
    }
    #pragma unroll
    for (int o = 32; o > 0; o >>= 1) bv += __shfl_down(bv, o);
    if (lane == 0 && wid < 12) bred[wid] = bv;
    __syncthreads();

    if (t < 52) {   // k = t>>2, b = t&3; 4 waves per b
        int k = t >> 2, b = t & 3;
        S[k * 4 + b] = (double)sred[k * 16 + b * 4]     + (double)sred[k * 16 + b * 4 + 1]
                     + (double)sred[k * 16 + b * 4 + 2] + (double)sred[k * 16 + b * 4 + 3];
    }
    __syncthreads();
    if (t == 0) {
        const double NV = (double)NVOX;
        double dice_sum = 0.0;
        for (int b = 0; b < 4; ++b)
            for (int c = 0; c < 4; ++c) {
                double inter = S[c * 4 + b];
                double un    = S[(4 + c) * 4 + b] + S[(8 + c) * 4 + b];
                dice_sum += (2.0 * inter + 1e-5) / (un + 1e-5);
            }
        double l_dice = 1.0 - dice_sum / 16.0;
        double l_ce = (S[48] + S[49] + S[50] + S[51]) / (4.0 * NV);
        double lb = 0.0;
        for (int cb = 0; cb < 12; ++cb) {
            int b = cb / 3, c = cb % 3 + 1;
            double cnt = S[(8 + c) * 4 + b];
            double s;
            if (cnt == 0.0)      s =  S[(4 + c) * 4 + b];   // sdf == +1 everywhere
            else if (cnt == NV)  s = -S[(4 + c) * 4 + b];   // sdf == -1 everywhere
            else                 s =  (double)bred[cb];
            lb += s / NV;
        }
        lb /= 12.0;
        out[0] = (float)(l_dice + l_ce + 0.01 * lb);
    }
}

extern "C" void kernel_launch(void* const* d_in, const int* in_sizes, int n_in,
                              void* d_out, int out_size, void* d_ws, size_t ws_size,
                              hipStream_t stream) {
    const float* preds   = (const float*)d_in[0];
    const int*   targets = (const int*)d_in[1];
    float* out = (float*)d_out;

    // workspace: bufA u16 (12.6 MB) | probsT bf16 (6.3 MB) | partials | sink
    unsigned short* bufA   = (unsigned short*)d_ws;
    unsigned short* probsT = bufA + (size_t)24 * NVOX;
    float* part_stats = (float*)(probsT + (size_t)12 * NVOX);
    float* part_bound = part_stats + 13 * 1024;
    float* sink       = part_bound + 768;

    kWarm<<<2048, 256, 0, stream>>>(preds, targets, sink);
    K1_fused<<<1792, 256, 0, stream>>>(preds, targets, bufA, probsT, part_stats);
    K2_edt3_sdf<<<768, 512, 0, stream>>>(bufA, probsT, part_bound);
    K3_final<<<1, 1024, 0, stream>>>(part_stats, part_bound, out);
}